// Round 11
// baseline (1389.806 us; speedup 1.0000x reference)
//
#include <hip/hip_runtime.h>
#include <math.h>

#define NROWS   65536
#define DIMS    64
#define KCODES  1024
#define RPB     32     // rows per vq_dist block

static constexpr size_t QST_OFF  = 0;         // quantized_st [65536*64]
static constexpr size_t LOSS_OFF = 4194304;   // loss scalar
static constexpr size_t PERP_OFF = 4194305;   // perplexity scalar
static constexpr size_t ENC_OFF  = 4194306;   // encodings [65536*1024]
static constexpr size_t IDX_OFF  = 71303170;  // encoding_indices [65536]
static constexpr size_t DIST_OFF = 71368706;  // distances [65536*1024]

// prep: blocks 0..255 -> xn per row (numpy pairwise, mul-then-add) + winners init;
//       block 256 -> enorm (sequential d, mul-then-add) + counts/sqsum zero.
__global__ __launch_bounds__(256) void prep(
    const float* __restrict__ x, const float* __restrict__ emb,
    float* __restrict__ enorm, float* __restrict__ xn,
    unsigned long long* __restrict__ winners, float* __restrict__ counts,
    float* __restrict__ sqsum)
{
    #pragma clang fp contract(off)
    const int tid = threadIdx.x;
    if (blockIdx.x < 256) {
        const int row = blockIdx.x * 256 + tid;
        const float* xr = x + (size_t)row * DIMS;
        float rr[8];
        #pragma unroll
        for (int j = 0; j < 8; ++j) { float v = xr[j]; rr[j] = v * v; }
        #pragma unroll
        for (int i = 8; i < 64; i += 8)
            #pragma unroll
            for (int j = 0; j < 8; ++j) { float v = xr[i + j]; float sq = v * v; rr[j] = rr[j] + sq; }
        xn[row] = ((rr[0] + rr[1]) + (rr[2] + rr[3])) + ((rr[4] + rr[5]) + (rr[6] + rr[7]));
        winners[row] = ~0ull;
    } else {
        #pragma unroll
        for (int c = 0; c < 4; ++c) {
            int k = c * 256 + tid;
            float s = 0.f;
            for (int d = 0; d < DIMS; ++d) {
                float e = emb[(size_t)d * KCODES + k];
                float sq = e * e;
                s = s + sq;
            }
            enorm[k] = s;
            counts[k] = 0.f;
        }
        if (tid == 0) sqsum[0] = 0.f;
    }
}

// Block = 32 rows x 512 k. Thread owns columns k0+tid and k0+256+tid, both
// PINNED in VGPRs via empty asm (compiler cannot rematerialize past it).
// x tile in LDS (broadcast ds_read_b128, lgkmcnt-only). Main loop issues NO
// global loads -> dist/enc stores are never waited on (pure fire-and-forget).
__global__ __launch_bounds__(256, 3) void vq_dist(
    const float* __restrict__ x, const float* __restrict__ emb,
    const float* __restrict__ enorm, const float* __restrict__ xn,
    float* __restrict__ out, unsigned long long* __restrict__ winners)
{
    #pragma clang fp contract(off)
    __shared__ __align__(16) float xs[RPB * DIMS];   // 8 KB, row-major
    __shared__ float xnl[RPB];

    const int tid  = threadIdx.x;
    const int lane = tid & 63;
    const int k0   = (blockIdx.x & 1) * 512;
    const size_t n0 = (size_t)(blockIdx.x >> 1) * RPB;

    // ---- prologue: ALL global loads ----
    {
        const float4* xg = (const float4*)(x + n0 * DIMS);
        float4 a = xg[tid], b = xg[tid + 256];
        ((float4*)xs)[tid] = a; ((float4*)xs)[tid + 256] = b;
    }
    if (tid < RPB) xnl[tid] = xn[n0 + tid];
    float ec0[DIMS], ec1[DIMS];
    #pragma unroll
    for (int d = 0; d < DIMS; ++d) {
        ec0[d] = emb[(size_t)d * KCODES + (k0 + tid)];
        ec1[d] = emb[(size_t)d * KCODES + (k0 + 256 + tid)];
    }
    float en0 = enorm[k0 + tid];
    float en1 = enorm[k0 + 256 + tid];
    // pin the e-columns into VGPRs: after this, reload/remat is illegal
    #pragma unroll
    for (int d = 0; d < DIMS; ++d) asm volatile("" : "+v"(ec0[d]), "+v"(ec1[d]));
    asm volatile("" : "+v"(en0), "+v"(en1));
    __syncthreads();

    // ---- main loop: 16 groups of 2 rows (4 independent fma chains) ----
    for (int g = 0; g < 16; ++g) {
        const int r0 = g * 2;
        float a00 = 0.f, a01 = 0.f, a10 = 0.f, a11 = 0.f;
        #pragma unroll
        for (int dq = 0; dq < 16; ++dq) {   // d ascending; single fma chain per (row,k)
            float4 x0 = *(const float4*)&xs[(r0 + 0) * DIMS + dq * 4];   // broadcast
            float4 x1 = *(const float4*)&xs[(r0 + 1) * DIMS + dq * 4];
            a00 = fmaf(x0.x, ec0[dq*4+0], a00); a00 = fmaf(x0.y, ec0[dq*4+1], a00);
            a00 = fmaf(x0.z, ec0[dq*4+2], a00); a00 = fmaf(x0.w, ec0[dq*4+3], a00);
            a01 = fmaf(x0.x, ec1[dq*4+0], a01); a01 = fmaf(x0.y, ec1[dq*4+1], a01);
            a01 = fmaf(x0.z, ec1[dq*4+2], a01); a01 = fmaf(x0.w, ec1[dq*4+3], a01);
            a10 = fmaf(x1.x, ec0[dq*4+0], a10); a10 = fmaf(x1.y, ec0[dq*4+1], a10);
            a10 = fmaf(x1.z, ec0[dq*4+2], a10); a10 = fmaf(x1.w, ec0[dq*4+3], a10);
            a11 = fmaf(x1.x, ec1[dq*4+0], a11); a11 = fmaf(x1.y, ec1[dq*4+1], a11);
            a11 = fmaf(x1.z, ec1[dq*4+2], a11); a11 = fmaf(x1.w, ec1[dq*4+3], a11);
        }
        #pragma unroll
        for (int j = 0; j < 2; ++j) {
            const float aa0 = j ? a10 : a00, aa1 = j ? a11 : a01;
            const int row = r0 + j;
            const float xnr = xnl[row];
            // np order: (xn - 2*M) + en, each op individually rounded
            float m0 = 2.0f * aa0; float t0 = xnr - m0; float dv0 = t0 + en0;
            float m1 = 2.0f * aa1; float t1 = xnr - m1; float dv1 = t1 + en1;
            const size_t rowg = n0 + row;
            float* dr = out + DIST_OFF + rowg * (size_t)KCODES + k0;
            dr[tid] = dv0; dr[tid + 256] = dv1;       // 256-lane contiguous dwords
            float* er = out + ENC_OFF + rowg * (size_t)KCODES + k0;
            er[tid] = 0.f; er[tid + 256] = 0.f;

            // wave argmin: fminf butterfly + ballot; smallest-k via ctz (col0 < col1)
            float rm = fminf(dv0, dv1);
            #pragma unroll
            for (int m = 1; m < 64; m <<= 1) rm = fminf(rm, __shfl_xor(rm, m));
            unsigned long long b0 = __ballot(dv0 == rm);
            unsigned long long b1 = __ballot(dv1 == rm);
            int winlane = b0 ? __builtin_ctzll(b0) : __builtin_ctzll(b1);
            if (lane == winlane) {
                int kw = b0 ? (k0 + tid) : (k0 + 256 + tid);
                int ib = __float_as_int(rm);
                unsigned mk = (unsigned)ib ^ ((unsigned)(ib >> 31) | 0x80000000u);
                unsigned long long key = ((unsigned long long)mk << 32) | (unsigned)kw;
                atomicMin(&winners[rowg], key);   // min value, then min k
            }
        }
    }
}

// Pass 2: unpack winners -> qst gather, idx, enc one-hot, counts, sqsum
__global__ __launch_bounds__(256) void vq_finish(
    const float* __restrict__ x, const float* __restrict__ emb,
    const unsigned long long* __restrict__ winners, float* __restrict__ out,
    float* __restrict__ counts, float* __restrict__ sqsum)
{
    __shared__ float bsum[4];
    const int tid = threadIdx.x;
    const size_t row = (size_t)blockIdx.x * 16 + (tid >> 4);
    const int q = tid & 15;
    const int k = (int)(winners[row] & 1023u);

    float4 e4;
    e4.x = emb[(size_t)(q * 4 + 0) * KCODES + k];
    e4.y = emb[(size_t)(q * 4 + 1) * KCODES + k];
    e4.z = emb[(size_t)(q * 4 + 2) * KCODES + k];
    e4.w = emb[(size_t)(q * 4 + 3) * KCODES + k];
    float4 x4 = *(const float4*)(x + row * DIMS + q * 4);
    *(float4*)(out + QST_OFF + row * DIMS + q * 4) = e4;

    float f0 = e4.x - x4.x, f1 = e4.y - x4.y, f2 = e4.z - x4.z, f3 = e4.w - x4.w;
    float ls = f0 * f0 + f1 * f1 + f2 * f2 + f3 * f3;
    #pragma unroll
    for (int m = 1; m < 64; m <<= 1) ls += __shfl_xor(ls, m);
    if ((tid & 63) == 0) bsum[tid >> 6] = ls;

    if (q == 0) {
        out[IDX_OFF + row] = (float)k;
        atomicAdd(&counts[k], 1.0f);
        out[ENC_OFF + row * (size_t)KCODES + k] = 1.0f;   // zeros by vq_dist (prior kernel)
    }
    __syncthreads();
    if (tid == 0) atomicAdd(sqsum, (bsum[0] + bsum[1]) + (bsum[2] + bsum[3]));
}

__global__ void vq_final(const float* __restrict__ counts, const float* __restrict__ sqsum,
                         float* __restrict__ out) {
    __shared__ double part[16];
    int tid = threadIdx.x;  // 1024 threads
    double p = (double)counts[tid] * (1.0 / 65536.0);
    double t = p * log(p + 1e-10);
    #pragma unroll
    for (int m = 1; m < 64; m <<= 1) t += __shfl_xor(t, m);
    if ((tid & 63) == 0) part[tid >> 6] = t;
    __syncthreads();
    if (tid == 0) {
        double s = 0.0;
        #pragma unroll
        for (int i = 0; i < 16; ++i) s += part[i];
        out[LOSS_OFF] = (float)(1.25 * (double)sqsum[0] * (1.0 / 4194304.0));
        out[PERP_OFF] = (float)exp(-s);
    }
}

extern "C" void kernel_launch(void* const* d_in, const int* in_sizes, int n_in,
                              void* d_out, int out_size, void* d_ws, size_t ws_size,
                              hipStream_t stream) {
    const float* x   = (const float*)d_in[0];   // (64,32,32,64) fp32
    const float* emb = (const float*)d_in[1];   // (64,1024) fp32
    float* out = (float*)d_out;
    // ws (floats): enorm[0,1024) | counts[1024,2048) | sqsum[2048] |
    // xn @4096 [65536] | winners u64 @ float-offset 69632 (512 KB)
    float* enorm  = (float*)d_ws;
    float* counts = enorm + KCODES;
    float* sqsum  = counts + KCODES;
    float* xn     = (float*)d_ws + 4096;
    unsigned long long* winners = (unsigned long long*)((float*)d_ws + 69632);

    prep<<<257, 256, 0, stream>>>(x, emb, enorm, xn, winners, counts, sqsum);
    vq_dist<<<(NROWS / RPB) * 2, 256, 0, stream>>>(x, emb, enorm, xn, out, winners);
    vq_finish<<<NROWS / 16, 256, 0, stream>>>(x, emb, winners, out, counts, sqsum);
    vq_final<<<1, KCODES, 0, stream>>>(counts, sqsum, out);
}

// Round 12
// 409.037 us; speedup vs baseline: 3.3978x; 3.3978x over previous
//
#include <hip/hip_runtime.h>
#include <math.h>

#define NROWS   65536
#define DIMS    64
#define KCODES  1024
#define RPB     256    // rows per vq_dist block

static constexpr size_t QST_OFF  = 0;         // quantized_st [65536*64]
static constexpr size_t LOSS_OFF = 4194304;   // loss scalar
static constexpr size_t PERP_OFF = 4194305;   // perplexity scalar
static constexpr size_t ENC_OFF  = 4194306;   // encodings [65536*1024]
static constexpr size_t IDX_OFF  = 71303170;  // encoding_indices [65536]
static constexpr size_t DIST_OFF = 71368706;  // distances [65536*1024]

// prep: blocks 0..255 -> xn per row (numpy pairwise, mul-then-add) + winners init;
//       block 256 -> enorm (sequential d, mul-then-add) + counts/sqsum zero.
__global__ __launch_bounds__(256) void prep(
    const float* __restrict__ x, const float* __restrict__ emb,
    float* __restrict__ enorm, float* __restrict__ xn,
    unsigned long long* __restrict__ winners, float* __restrict__ counts,
    float* __restrict__ sqsum)
{
    #pragma clang fp contract(off)
    const int tid = threadIdx.x;
    if (blockIdx.x < 256) {
        const int row = blockIdx.x * 256 + tid;
        const float* xr = x + (size_t)row * DIMS;
        float rr[8];
        #pragma unroll
        for (int j = 0; j < 8; ++j) { float v = xr[j]; rr[j] = v * v; }
        #pragma unroll
        for (int i = 8; i < 64; i += 8)
            #pragma unroll
            for (int j = 0; j < 8; ++j) { float v = xr[i + j]; float sq = v * v; rr[j] = rr[j] + sq; }
        xn[row] = ((rr[0] + rr[1]) + (rr[2] + rr[3])) + ((rr[4] + rr[5]) + (rr[6] + rr[7]));
        winners[row] = ~0ull;
    } else {
        #pragma unroll
        for (int c = 0; c < 4; ++c) {
            int k = c * 256 + tid;
            float s = 0.f;
            for (int d = 0; d < DIMS; ++d) {
                float e = emb[(size_t)d * KCODES + k];
                float sq = e * e;
                s = s + sq;
            }
            enorm[k] = s;
            counts[k] = 0.f;
        }
        if (tid == 0) sqsum[0] = 0.f;
    }
}

// Block = 256 rows x 256 k. Thread owns ONE e-column (64 VGPR), pinned.
// NO __launch_bounds__ minimum: allocator has the full 256-VGPR budget for a
// ~90-VGPR kernel -> no spill, no remat. x-row is read through wave-uniform
// pointers -> s_load (SMEM/lgkmcnt), so the row loop issues ZERO vmcnt loads
// and the dist/enc stores are pure fire-and-forget.
__global__ __launch_bounds__(256) void vq_dist(
    const float* __restrict__ x, const float* __restrict__ emb,
    const float* __restrict__ enorm, const float* __restrict__ xn,
    float* __restrict__ out, unsigned long long* __restrict__ winners)
{
    #pragma clang fp contract(off)
    const int tid  = threadIdx.x;
    const int lane = tid & 63;
    const int k    = (blockIdx.x & 3) * 256 + tid;     // this thread's code
    const size_t n0 = (size_t)(blockIdx.x >> 2) * RPB;

    // ---- prologue: the only vector global loads ----
    float ec[DIMS];
    #pragma unroll
    for (int d = 0; d < DIMS; ++d) ec[d] = emb[(size_t)d * KCODES + k];   // coalesced
    float en = enorm[k];
    #pragma unroll
    for (int d = 0; d < DIMS; ++d) asm volatile("" : "+v"(ec[d]));
    asm volatile("" : "+v"(en));

    for (int r = 0; r < RPB; ++r) {
        const size_t row = n0 + r;
        const float* __restrict__ xr = x + row * DIMS;   // wave-uniform -> s_load
        float acc = 0.f;
        #pragma unroll
        for (int dq = 0; dq < 16; ++dq) {   // d ascending: numpy/BLAS fma chain
            float4 xq = *(const float4*)(xr + dq * 4);   // s_load_dwordx4
            acc = fmaf(xq.x, ec[dq * 4 + 0], acc);
            acc = fmaf(xq.y, ec[dq * 4 + 1], acc);
            acc = fmaf(xq.z, ec[dq * 4 + 2], acc);
            acc = fmaf(xq.w, ec[dq * 4 + 3], acc);
        }
        const float xnr = xn[row];          // uniform -> s_load
        // np order: (xn - 2*M) + en, each op individually rounded
        float mm = 2.0f * acc;
        float tt = xnr - mm;
        float dv = tt + en;

        out[DIST_OFF + row * (size_t)KCODES + k] = dv;   // 256-lane contiguous dwords
        out[ENC_OFF  + row * (size_t)KCODES + k] = 0.f;

        // wave argmin over its 64 contiguous k: fminf butterfly + ballot/ctz
        float rm = dv;
        #pragma unroll
        for (int m = 1; m < 64; m <<= 1) rm = fminf(rm, __shfl_xor(rm, m));
        unsigned long long b = __ballot(dv == rm);
        if (lane == __builtin_ctzll(b)) {   // lowest lane = lowest k among ties
            int ib = __float_as_int(rm);
            unsigned mk = (unsigned)ib ^ ((unsigned)(ib >> 31) | 0x80000000u);
            unsigned long long key = ((unsigned long long)mk << 32) | (unsigned)k;
            atomicMin(&winners[row], key);   // min value, then min k (tie)
        }
    }
}

// Pass 2: unpack winners -> qst gather, idx, enc one-hot, counts, sqsum
__global__ __launch_bounds__(256) void vq_finish(
    const float* __restrict__ x, const float* __restrict__ emb,
    const unsigned long long* __restrict__ winners, float* __restrict__ out,
    float* __restrict__ counts, float* __restrict__ sqsum)
{
    __shared__ float bsum[4];
    const int tid = threadIdx.x;
    const size_t row = (size_t)blockIdx.x * 16 + (tid >> 4);
    const int q = tid & 15;
    const int k = (int)(winners[row] & 1023u);

    float4 e4;
    e4.x = emb[(size_t)(q * 4 + 0) * KCODES + k];
    e4.y = emb[(size_t)(q * 4 + 1) * KCODES + k];
    e4.z = emb[(size_t)(q * 4 + 2) * KCODES + k];
    e4.w = emb[(size_t)(q * 4 + 3) * KCODES + k];
    float4 x4 = *(const float4*)(x + row * DIMS + q * 4);
    *(float4*)(out + QST_OFF + row * DIMS + q * 4) = e4;

    float f0 = e4.x - x4.x, f1 = e4.y - x4.y, f2 = e4.z - x4.z, f3 = e4.w - x4.w;
    float ls = f0 * f0 + f1 * f1 + f2 * f2 + f3 * f3;
    #pragma unroll
    for (int m = 1; m < 64; m <<= 1) ls += __shfl_xor(ls, m);
    if ((tid & 63) == 0) bsum[tid >> 6] = ls;

    if (q == 0) {
        out[IDX_OFF + row] = (float)k;
        atomicAdd(&counts[k], 1.0f);
        out[ENC_OFF + row * (size_t)KCODES + k] = 1.0f;   // zeros by vq_dist (prior kernel)
    }
    __syncthreads();
    if (tid == 0) atomicAdd(sqsum, (bsum[0] + bsum[1]) + (bsum[2] + bsum[3]));
}

__global__ void vq_final(const float* __restrict__ counts, const float* __restrict__ sqsum,
                         float* __restrict__ out) {
    __shared__ double part[16];
    int tid = threadIdx.x;  // 1024 threads
    double p = (double)counts[tid] * (1.0 / 65536.0);
    double t = p * log(p + 1e-10);
    #pragma unroll
    for (int m = 1; m < 64; m <<= 1) t += __shfl_xor(t, m);
    if ((tid & 63) == 0) part[tid >> 6] = t;
    __syncthreads();
    if (tid == 0) {
        double s = 0.0;
        #pragma unroll
        for (int i = 0; i < 16; ++i) s += part[i];
        out[LOSS_OFF] = (float)(1.25 * (double)sqsum[0] * (1.0 / 4194304.0));
        out[PERP_OFF] = (float)exp(-s);
    }
}

extern "C" void kernel_launch(void* const* d_in, const int* in_sizes, int n_in,
                              void* d_out, int out_size, void* d_ws, size_t ws_size,
                              hipStream_t stream) {
    const float* x   = (const float*)d_in[0];   // (64,32,32,64) fp32
    const float* emb = (const float*)d_in[1];   // (64,1024) fp32
    float* out = (float*)d_out;
    // ws (floats): enorm[0,1024) | counts[1024,2048) | sqsum[2048] |
    // xn @4096 [65536] | winners u64 @ float-offset 69632 (512 KB)
    float* enorm  = (float*)d_ws;
    float* counts = enorm + KCODES;
    float* sqsum  = counts + KCODES;
    float* xn     = (float*)d_ws + 4096;
    unsigned long long* winners = (unsigned long long*)((float*)d_ws + 69632);

    prep<<<257, 256, 0, stream>>>(x, emb, enorm, xn, winners, counts, sqsum);
    vq_dist<<<(NROWS / RPB) * 4, 256, 0, stream>>>(x, emb, enorm, xn, out, winners);
    vq_finish<<<NROWS / 16, 256, 0, stream>>>(x, emb, winners, out, counts, sqsum);
    vq_final<<<1, KCODES, 0, stream>>>(counts, sqsum, out);
}